// Round 1
// baseline (495.997 us; speedup 1.0000x reference)
//
#include <hip/hip_runtime.h>
#include <hip/hip_bf16.h>
#include <stdint.h>

// Problem constants: M=512, P=256, B=128, T=1024
#define NB   128
#define NT   1024
#define NM   512
#define NP   256

typedef __attribute__((ext_vector_type(8))) short bf16x8;
typedef __attribute__((ext_vector_type(4))) float f32x4;

__device__ __forceinline__ unsigned short f2bf(float f) {
    union { float f; uint32_t u; } x; x.f = f;
    uint32_t u = x.u + 0x7FFFu + ((x.u >> 16) & 1u);   // RNE
    return (unsigned short)(u >> 16);
}

// ---------- Kernel 1: convert U (512x512 f32 row-major [n][m]) -> bf16 ----------
__global__ void cvt_u_kernel(const float* __restrict__ U, unsigned short* __restrict__ Ub) {
    int idx = blockIdx.x * blockDim.x + threadIdx.x;   // 0..65535, 4 elems each
    float4 u = reinterpret_cast<const float4*>(U)[idx];
    ushort4 o;
    o.x = f2bf(u.x); o.y = f2bf(u.y); o.z = f2bf(u.z); o.w = f2bf(u.w);
    reinterpret_cast<ushort4*>(Ub)[idx] = o;
}

// ---------- Kernel 2: wq[b][n] = sum_c q[b][c] * W[n][c], q = [d_t | s_t] (fp32, exact) ----------
__global__ void wq_kernel(const float* __restrict__ d_t, const float* __restrict__ s_t,
                          const float* __restrict__ W, float* __restrict__ wq) {
    int g = blockIdx.x * blockDim.x + threadIdx.x;     // 0..65535
    int b = g >> 9;
    int n = g & 511;
    const float* Wn = W + (size_t)n * 512;
    const float* dt = d_t + (size_t)b * NP;
    const float* st = s_t + (size_t)b * NP;
    float s = 0.f;
    #pragma unroll 4
    for (int c = 0; c < NP; c += 4) {
        float4 w0 = *reinterpret_cast<const float4*>(Wn + c);
        float4 q0 = *reinterpret_cast<const float4*>(dt + c);
        s += w0.x * q0.x + w0.y * q0.y + w0.z * q0.z + w0.w * q0.w;
        float4 w1 = *reinterpret_cast<const float4*>(Wn + NP + c);
        float4 q1 = *reinterpret_cast<const float4*>(st + c);
        s += w1.x * q1.x + w1.y * q1.y + w1.z * q1.z + w1.w * q1.w;
    }
    wq[g] = s;
}

// ---------- Kernel 3: per (b, 64-row t-tile): C = H_tile * U^T (bf16 MFMA, full N=512),
//                      then score[t] = sum_n v[n]*tanh(wq[n] + C[t,n]) ----------
// WG: 256 threads = 4 waves; wave w covers t 0..63 x n [w*128, w*128+128)
// LDS rows padded 32->40 (+16B) : 2-way bank aliasing on ds_read_b128 (free per m136)
__global__ __launch_bounds__(256, 2)
void score_kernel(const float* __restrict__ H, const unsigned short* __restrict__ Ub,
                  const float* __restrict__ wq, const float* __restrict__ v_d,
                  float* __restrict__ out) {
    __shared__ unsigned short As[64 * 40];
    __shared__ unsigned short Bs[512 * 40];
    __shared__ float s_score[64];

    const int tid  = threadIdx.x;
    const int b    = blockIdx.y;
    const int t0   = blockIdx.x * 64;
    const int lane = tid & 63;
    const int w    = tid >> 6;      // wave id = n-quadrant
    const int lr   = lane & 15;
    const int lq   = lane >> 4;

    const float* Hb = H + ((size_t)b * NT + t0) * NM;

    f32x4 acc[4][8];
    #pragma unroll
    for (int i = 0; i < 4; ++i)
        #pragma unroll
        for (int j = 0; j < 8; ++j)
            acc[i][j] = (f32x4){0.f, 0.f, 0.f, 0.f};

    for (int kk = 0; kk < 16; ++kk) {
        const int m0 = kk * 32;
        // stage A: 64 x 32 fp32 -> bf16 LDS (2 float4 per thread)
        #pragma unroll
        for (int i = 0; i < 2; ++i) {
            int idx = tid + i * 256;            // 0..511
            int r   = idx >> 3;                 // 0..63
            int c4  = (idx & 7) * 4;            // 0..28
            float4 v = *reinterpret_cast<const float4*>(Hb + (size_t)r * NM + m0 + c4);
            ushort4 o;
            o.x = f2bf(v.x); o.y = f2bf(v.y); o.z = f2bf(v.z); o.w = f2bf(v.w);
            *reinterpret_cast<ushort4*>(&As[r * 40 + c4]) = o;
        }
        // stage B: 512 x 32 bf16 (8 x 16B per thread)
        #pragma unroll
        for (int i = 0; i < 8; ++i) {
            int idx = tid + i * 256;            // 0..2047
            int r   = idx >> 2;                 // 0..511
            int c8  = (idx & 3) * 8;            // 0,8,16,24
            int4 vv = *reinterpret_cast<const int4*>(Ub + (size_t)r * NM + m0 + c8);
            *reinterpret_cast<int4*>(&Bs[r * 40 + c8]) = vv;
        }
        __syncthreads();

        // fragments: A[m=lr][k=lq*8+j], B[k=lq*8+j][n=lr]  (16B ds_read each)
        bf16x8 a[4], bq[8];
        #pragma unroll
        for (int i = 0; i < 4; ++i)
            a[i] = *reinterpret_cast<const bf16x8*>(&As[(i * 16 + lr) * 40 + lq * 8]);
        #pragma unroll
        for (int j = 0; j < 8; ++j)
            bq[j] = *reinterpret_cast<const bf16x8*>(&Bs[(w * 128 + j * 16 + lr) * 40 + lq * 8]);
        #pragma unroll
        for (int i = 0; i < 4; ++i)
            #pragma unroll
            for (int j = 0; j < 8; ++j)
                acc[i][j] = __builtin_amdgcn_mfma_f32_16x16x32_bf16(a[i], bq[j], acc[i][j], 0, 0, 0);
        __syncthreads();
    }

    // Epilogue: C/D layout col = lane&15 (n), row = (lane>>4)*4 + reg (t)
    if (tid < 64) s_score[tid] = 0.f;
    __syncthreads();

    const float* wqb = wq + (size_t)b * NM;
    float vv[8], wv[8];
    #pragma unroll
    for (int j = 0; j < 8; ++j) {
        int n = w * 128 + j * 16 + lr;
        vv[j] = v_d[n];
        wv[j] = wqb[n];
    }
    #pragma unroll
    for (int i = 0; i < 4; ++i) {
        #pragma unroll
        for (int r = 0; r < 4; ++r) {
            float s = 0.f;
            #pragma unroll
            for (int j = 0; j < 8; ++j)
                s += vv[j] * tanhf(wv[j] + acc[i][j][r]);
            #pragma unroll
            for (int off = 1; off < 16; off <<= 1)
                s += __shfl_xor(s, off, 64);
            if (lr == 0) atomicAdd(&s_score[i * 16 + lq * 4 + r], s);
        }
    }
    __syncthreads();
    if (tid < 64) out[(size_t)b * NT + t0 + tid] = s_score[tid];
}

// ---------- Kernel 4: softmax over T=1024, in place on d_out, one WG per b ----------
__global__ void softmax_kernel(float* __restrict__ out) {
    const int b   = blockIdx.x;
    const int tid = threadIdx.x;          // 256 threads x 4 elems
    float* p = out + (size_t)b * NT;
    float4 v = reinterpret_cast<float4*>(p)[tid];
    float m = fmaxf(fmaxf(v.x, v.y), fmaxf(v.z, v.w));
    #pragma unroll
    for (int off = 32; off >= 1; off >>= 1)
        m = fmaxf(m, __shfl_xor(m, off, 64));
    __shared__ float red[8];
    const int wv = tid >> 6;
    if ((tid & 63) == 0) red[wv] = m;
    __syncthreads();
    m = fmaxf(fmaxf(red[0], red[1]), fmaxf(red[2], red[3]));
    float e0 = __expf(v.x - m), e1 = __expf(v.y - m);
    float e2 = __expf(v.z - m), e3 = __expf(v.w - m);
    float s = e0 + e1 + e2 + e3;
    #pragma unroll
    for (int off = 32; off >= 1; off >>= 1)
        s += __shfl_xor(s, off, 64);
    if ((tid & 63) == 0) red[4 + wv] = s;
    __syncthreads();
    s = red[4] + red[5] + red[6] + red[7];
    float inv = 1.f / s;
    float4 o;
    o.x = e0 * inv; o.y = e1 * inv; o.z = e2 * inv; o.w = e3 * inv;
    reinterpret_cast<float4*>(p)[tid] = o;
}

extern "C" void kernel_launch(void* const* d_in, const int* in_sizes, int n_in,
                              void* d_out, int out_size, void* d_ws, size_t ws_size,
                              hipStream_t stream) {
    const float* d_t = (const float*)d_in[0];
    const float* s_t = (const float*)d_in[1];
    const float* H   = (const float*)d_in[2];
    // d_in[3] = T (scalar, 1024) — shapes are hard-coded
    const float* W_d = (const float*)d_in[4];
    const float* U_d = (const float*)d_in[5];
    const float* v_d = (const float*)d_in[6];
    float* out = (float*)d_out;

    unsigned short* Ub = (unsigned short*)d_ws;              // 512 KB bf16 U
    float* wq = (float*)((char*)d_ws + 512 * 1024);          // 256 KB fp32 wq

    cvt_u_kernel<<<256, 256, 0, stream>>>(U_d, Ub);
    wq_kernel<<<256, 256, 0, stream>>>(d_t, s_t, W_d, wq);
    score_kernel<<<dim3(NT / 64, NB), 256, 0, stream>>>(H, Ub, wq, v_d, out);
    softmax_kernel<<<NB, 256, 0, stream>>>(out);
}